// Round 18
// baseline (187.492 us; speedup 1.0000x reference)
//
#include <hip/hip_runtime.h>
#include <hip/hip_bf16.h>
#include <stdint.h>

#define DEVINLINE __device__ __forceinline__

typedef __attribute__((ext_vector_type(4))) float f32x4;
typedef __attribute__((ext_vector_type(8))) short bf16x8;

DEVINLINE unsigned short f2bf(float f) {
    union { float f; uint32_t u; } v; v.f = f;
    uint32_t u = v.u;
    uint32_t rounding = 0x7FFFu + ((u >> 16) & 1u);
    u += rounding;
    return (unsigned short)(u >> 16);
}

DEVINLINE float bf2f(unsigned short h) {
    union { uint32_t u; float f; } v; v.u = ((uint32_t)h) << 16;
    return v.f;
}

// ---------------- fused prep: x cvt (grid-stride) + w_qkv transpose + w_o transpose ----------------
#define NCVT 1024
__global__ __launch_bounds__(256)
void prep_kernel(const float* __restrict__ x, unsigned short* __restrict__ xb, int n,
                 const float* __restrict__ wq, unsigned short* __restrict__ wqT,
                 const float* __restrict__ wo, unsigned short* __restrict__ woT) {
    int b = blockIdx.x;
    if (b < NCVT) {
        int i = (b * 256 + threadIdx.x) * 4;
        int stride = NCVT * 256 * 4;
        for (; i < n; i += stride) {
            float4 v = *reinterpret_cast<const float4*>(x + i);
            ushort4 o;
            o.x = f2bf(v.x); o.y = f2bf(v.y); o.z = f2bf(v.z); o.w = f2bf(v.w);
            *reinterpret_cast<ushort4*>(xb + i) = o;
        }
        return;
    }
    __shared__ float tile[32][33];
    const float* in;
    unsigned short* outp;
    int R, Ccols, tb;
    if (b < NCVT + 96 * 32) {
        tb = b - NCVT; in = wq; outp = wqT; R = 1024; Ccols = 3072;
    } else {
        tb = b - NCVT - 96 * 32; in = wo; outp = woT; R = 1024; Ccols = 1024;
    }
    int ntx = Ccols / 32;
    int c0 = (tb % ntx) * 32, r0 = (tb / ntx) * 32;
    int tx = threadIdx.x & 31, ty = threadIdx.x >> 5; // 32 x 8
    #pragma unroll
    for (int j = 0; j < 32; j += 8)
        tile[ty + j][tx] = in[(size_t)(r0 + ty + j) * Ccols + c0 + tx];
    __syncthreads();
    #pragma unroll
    for (int j = 0; j < 32; j += 8)
        outp[(size_t)(c0 + ty + j) * R + r0 + tx] = f2bf(tile[tx][ty + j]);
}

// ============ 256x256 bf16 GEMM, read-ahead pipelined (R5/R7 schedule) ============
// 8 waves (2M x 4N), BK=64, 128 KiB LDS double-buffered.
// Phase p = { MMA(quadrant p); ds_reads for phase p+1; [stages]; [vmcnt]; s_barrier }.
// setprio REMOVED this round (T5 is null-to-negative on lockstep GEMM structures, m190):
// without the fence the compiler can interleave read-ahead ds_reads into the MFMA window.

#define GLD(srcp, dstp) __builtin_amdgcn_global_load_lds( \
    (const __attribute__((address_space(1))) void*)(srcp), \
    (__attribute__((address_space(3))) void*)(dstp), 16, 0, 0)

// stage one half-tile (128 rows x 64 cols bf16): 2 loads x 8 waves
#define STAGE(P, regionUS, srcBase, row0, kkE) do { \
    const unsigned short* _s = (srcBase) + (size_t)(row0) * K + (kkE); \
    unsigned short* _d = lds + (P) * 32768 + (regionUS) + wid * 512; \
    GLD(_s, _d); GLD(_s + (size_t)64 * K, _d + 4096); } while (0)

#define RD_A(dst, AS0, AS1, h) do { _Pragma("unroll") \
    for (int _i = 0; _i < 4; ++_i) { \
        dst[_i][0] = *(const bf16x8*)((AS0) + ((h) * 8192 + _i * 2048)); \
        dst[_i][1] = *(const bf16x8*)((AS1) + ((h) * 8192 + _i * 2048)); } } while (0)

#define RD_B(dst, BS0, BS1, nh) do { _Pragma("unroll") \
    for (int _j = 0; _j < 2; ++_j) { \
        dst[_j][0] = *(const bf16x8*)((BS0) + ((nh) * 4096 + _j * 2048)); \
        dst[_j][1] = *(const bf16x8*)((BS1) + ((nh) * 4096 + _j * 2048)); } } while (0)

#define MMA(aX, bY, mh, nh) do { \
    _Pragma("unroll") for (int _i = 0; _i < 4; ++_i) { \
    _Pragma("unroll") for (int _j = 0; _j < 2; ++_j) { \
        acc[(mh)*4+_i][(nh)*2+_j] = __builtin_amdgcn_mfma_f32_16x16x32_bf16( \
            aX[_i][0], bY[_j][0], acc[(mh)*4+_i][(nh)*2+_j], 0, 0, 0); \
        acc[(mh)*4+_i][(nh)*2+_j] = __builtin_amdgcn_mfma_f32_16x16x32_bf16( \
            aX[_i][1], bY[_j][1], acc[(mh)*4+_i][(nh)*2+_j], 0, 0, 0); } } \
    } while (0)

#define VM4 asm volatile("s_waitcnt vmcnt(4)" ::: "memory")
#define BAR() asm volatile("s_barrier" ::: "memory")

// One K-tile, parity-static LDS addresses. kk = clamped stage source column (elems).
#define KTILE(AS0c, AS1c, BS0c, BS1c, AS0n, AS1n, BS0n, BS1n, Pc, kk) do { \
    MMA(aA, bA, 0, 0); \
    RD_B(bB, BS0c, BS1c, 1); \
    BAR(); \
    MMA(aA, bB, 0, 1); \
    RD_A(aB, AS0c, AS1c, 1); \
    VM4; BAR(); \
    MMA(aB, bA, 1, 0); \
    RD_B(bA, BS0n, BS1n, 0); \
    STAGE(Pc, 16384, bSrc, 0,   kk); \
    STAGE(Pc, 24576, bSrc, 128, kk); \
    VM4; BAR(); \
    MMA(aB, bB, 1, 1); \
    RD_A(aA, AS0n, AS1n, 0); \
    STAGE(Pc, 0,     aSrc, 0,   kk); \
    STAGE(Pc, 8192,  aSrc, 128, kk); \
    BAR(); } while (0)

template <bool OUT_BF16>
__launch_bounds__(512, 2)
__global__ void gemm256(const unsigned short* __restrict__ A,
                        const unsigned short* __restrict__ Bt,
                        const float* __restrict__ bias,
                        void* __restrict__ Cout,
                        int M, int N, int K, int NTN) {
    __shared__ unsigned short lds[65536]; // 128 KiB: 2 buf x (A 256x64 + B 256x64)
    const int NT = K >> 6;                // K-tiles (even, >= 2)

    int t = threadIdx.x;
    int wid = t >> 6, lane = t & 63;
    int wr = wid >> 2, wc = wid & 3;
    int fr = lane & 15, fq = lane >> 4;

    // XCD-aware block swizzle (grid % 8 == 0)
    int nwg = gridDim.x, bid = blockIdx.x;
    int cpx = nwg >> 3;
    int swz = (bid & 7) * cpx + (bid >> 3);
    int tm = swz / NTN, tn = swz % NTN;
    int bm = tm * 256, bn = tn * 256;

    // staging source (per-lane, pre-swizzled 16B slot)
    int rowl = t >> 3, col8 = t & 7;
    int swzcol = (col8 ^ (rowl & 7)) << 3;
    const unsigned short* aSrc = A + (size_t)(bm + rowl) * K + swzcol;
    const unsigned short* bSrc = Bt + (size_t)(bn + rowl) * K + swzcol;

    // ds_read swizzled base pointers (row&7 == fr&7 for all fragment rows)
    int swzm = (fr & 7) << 3;
    int colS0 = (fq << 3) ^ swzm;
    int colS1 = (32 | (fq << 3)) ^ swzm;

    char* ldsb = (char*)lds;
    char* A00 = ldsb + ((wr * 128 + fr) << 7) + 2 * colS0;
    char* A10 = ldsb + ((wr * 128 + fr) << 7) + 2 * colS1;
    char* B00 = ldsb + ((256 + wc * 64 + fr) << 7) + 2 * colS0;
    char* B10 = ldsb + ((256 + wc * 64 + fr) << 7) + 2 * colS1;
    char* A01 = A00 + 65536; char* A11 = A10 + 65536;
    char* B01 = B00 + 65536; char* B11 = B10 + 65536;

    f32x4 acc[8][4] = {};
    bf16x8 aA[4][2], aB[4][2], bA[2][2], bB[2][2];

    // ---- prologue: 16 loads = tiles 0 and 1, order A(0),B(0),B(1),A(1) ----
    STAGE(0, 0,     aSrc, 0,   0);   // A0(0)
    STAGE(0, 8192,  aSrc, 128, 0);   // A1(0)
    STAGE(0, 16384, bSrc, 0,   0);   // B0(0)
    STAGE(0, 24576, bSrc, 128, 0);   // B1(0)
    STAGE(1, 16384, bSrc, 0,   64);  // B0(1)
    STAGE(1, 24576, bSrc, 128, 64);  // B1(1)
    STAGE(1, 0,     aSrc, 0,   64);  // A0(1)
    STAGE(1, 8192,  aSrc, 128, 64);  // A1(1)
    asm volatile("s_waitcnt vmcnt(8)" ::: "memory"); // A(0),B(0) landed
    BAR();
    RD_A(aA, A00, A10, 0);   // A(0) h=0
    RD_B(bA, B00, B10, 0);   // B(0) nh=0

    for (int tau = 0; tau < NT; tau += 2) {
        int kkA = ((tau + 2 < NT) ? (tau + 2) : (NT - 1)) << 6;
        KTILE(A00, A10, B00, B10, A01, A11, B01, B11, 0, kkA);
        int kkB = ((tau + 3 < NT) ? (tau + 3) : (NT - 1)) << 6;
        KTILE(A01, A11, B01, B11, A00, A10, B00, B10, 1, kkB);
    }
    asm volatile("s_waitcnt vmcnt(0)" ::: "memory");

    // ---- epilogue: bias + store ----
    #pragma unroll
    for (int m = 0; m < 8; ++m) {
        #pragma unroll
        for (int n = 0; n < 4; ++n) {
            int col = bn + wc * 64 + n * 16 + fr;
            float bv = bias[col];
            #pragma unroll
            for (int r = 0; r < 4; ++r) {
                int row = bm + wr * 128 + m * 16 + fq * 4 + r;
                float v = acc[m][n][r] + bv;
                if (OUT_BF16)
                    ((unsigned short*)Cout)[(size_t)row * N + col] = f2bf(v);
                else
                    ((float*)Cout)[(size_t)row * N + col] = v;
            }
        }
    }
}

// ---------------- per-position head-mixing attention (MFMA QK^T, 4 pos/block) ----------------
__global__ __launch_bounds__(256)
void attn_kernel(const unsigned short* __restrict__ qkv,
                 unsigned short* __restrict__ out) {
    __shared__ float sv[4][16][68];   // per-wave; row stride 272B (16B-aligned)
    __shared__ float sp[4][16][17];
    int wv = threadIdx.x >> 6;
    int l = threadIdx.x & 63;
    int pos = blockIdx.x * 4 + wv;
    const unsigned short* rowp = qkv + (size_t)pos * 3072;

    #pragma unroll
    for (int j = 0; j < 2; ++j) {
        int i8 = (j * 64 + l) * 8;        // 0..1016
        int h = i8 >> 6, d = i8 & 63;     // h = 0..15
        ushort4 v0 = *reinterpret_cast<const ushort4*>(rowp + h * 192 + 128 + d);
        ushort4 v1 = *reinterpret_cast<const ushort4*>(rowp + h * 192 + 128 + d + 4);
        sv[wv][h][d + 0] = bf2f(v0.x); sv[wv][h][d + 1] = bf2f(v0.y);
        sv[wv][h][d + 2] = bf2f(v0.z); sv[wv][h][d + 3] = bf2f(v0.w);
        sv[wv][h][d + 4] = bf2f(v1.x); sv[wv][h][d + 5] = bf2f(v1.y);
        sv[wv][h][d + 6] = bf2f(v1.z); sv[wv][h][d + 7] = bf2f(v1.w);
    }

    int fr = l & 15, fq = l >> 4;
    const unsigned short* hb = rowp + fr * 192 + fq * 8;
    bf16x8 kf0 = *reinterpret_cast<const bf16x8*>(hb + 64);
    bf16x8 kf1 = *reinterpret_cast<const bf16x8*>(hb + 96);
    bf16x8 qf0 = *reinterpret_cast<const bf16x8*>(hb);
    bf16x8 qf1 = *reinterpret_cast<const bf16x8*>(hb + 32);
    f32x4 st = {};
    st = __builtin_amdgcn_mfma_f32_16x16x32_bf16(kf0, qf0, st, 0, 0, 0);
    st = __builtin_amdgcn_mfma_f32_16x16x32_bf16(kf1, qf1, st, 0, 0, 0);

    float s0 = st[0] * 0.03125f, s1 = st[1] * 0.03125f;
    float s2 = st[2] * 0.03125f, s3 = st[3] * 0.03125f;
    float m = fmaxf(fmaxf(s0, s1), fmaxf(s2, s3));
    m = fmaxf(m, __shfl_xor(m, 16));
    m = fmaxf(m, __shfl_xor(m, 32));
    float e0 = __expf(s0 - m), e1 = __expf(s1 - m);
    float e2 = __expf(s2 - m), e3 = __expf(s3 - m);
    float sum = e0 + e1 + e2 + e3;
    sum += __shfl_xor(sum, 16);
    sum += __shfl_xor(sum, 32);
    float inv = 1.0f / sum;
    sp[wv][fr][fq * 4 + 0] = e0 * inv;
    sp[wv][fr][fq * 4 + 1] = e1 * inv;
    sp[wv][fr][fq * 4 + 2] = e2 * inv;
    sp[wv][fr][fq * 4 + 3] = e3 * inv;
    __syncthreads();

    int h2 = l >> 2, tq = l & 3;
    int dbase = tq * 16;
    float4 o0 = {}, o1 = {}, o2 = {}, o3 = {};
    #pragma unroll
    for (int tt = 0; tt < 16; ++tt) {
        float p = sp[wv][h2][tt];
        float4 v0 = *reinterpret_cast<const float4*>(&sv[wv][tt][dbase + 0]);
        float4 v1 = *reinterpret_cast<const float4*>(&sv[wv][tt][dbase + 4]);
        float4 v2 = *reinterpret_cast<const float4*>(&sv[wv][tt][dbase + 8]);
        float4 v3 = *reinterpret_cast<const float4*>(&sv[wv][tt][dbase + 12]);
        o0.x += p * v0.x; o0.y += p * v0.y; o0.z += p * v0.z; o0.w += p * v0.w;
        o1.x += p * v1.x; o1.y += p * v1.y; o1.z += p * v1.z; o1.w += p * v1.w;
        o2.x += p * v2.x; o2.y += p * v2.y; o2.z += p * v2.z; o2.w += p * v2.w;
        o3.x += p * v3.x; o3.y += p * v3.y; o3.z += p * v3.z; o3.w += p * v3.w;
    }
    ushort4* po = (ushort4*)(out + (size_t)pos * 1024 + h2 * 64 + dbase);
    ushort4 w0 = { f2bf(o0.x), f2bf(o0.y), f2bf(o0.z), f2bf(o0.w) };
    ushort4 w1 = { f2bf(o1.x), f2bf(o1.y), f2bf(o1.z), f2bf(o1.w) };
    ushort4 w2 = { f2bf(o2.x), f2bf(o2.y), f2bf(o2.z), f2bf(o2.w) };
    ushort4 w3 = { f2bf(o3.x), f2bf(o3.y), f2bf(o3.z), f2bf(o3.w) };
    po[0] = w0; po[1] = w1; po[2] = w2; po[3] = w3;
}

extern "C" void kernel_launch(void* const* d_in, const int* in_sizes, int n_in,
                              void* d_out, int out_size, void* d_ws, size_t ws_size,
                              hipStream_t stream) {
    const float* x     = (const float*)d_in[0];
    const float* w_qkv = (const float*)d_in[1];
    const float* b_qkv = (const float*)d_in[2];
    const float* w_o   = (const float*)d_in[3];
    const float* b_o   = (const float*)d_in[4];
    float* out = (float*)d_out;

    const int C = 1024, E = 1024;
    const int M = 16 * 1024;      // B*S = 16384
    const int N1 = 3 * E;         // 3072

    char* ws = (char*)d_ws;
    unsigned short* xb    = (unsigned short*)ws;            // M*C bf16
    unsigned short* wqkvT = xb    + (size_t)M * C;          // N1*C
    unsigned short* qkv   = wqkvT + (size_t)N1 * C;         // M*N1
    unsigned short* woT   = qkv   + (size_t)M * N1;         // E*E
    unsigned short* aout  = woT   + (size_t)E * E;          // M*E

    prep_kernel<<<NCVT + 96 * 32 + 32 * 32, 256, 0, stream>>>(
        x, xb, M * C, w_qkv, wqkvT, w_o, woT);

    // QKV: M=16384, N=3072, K=1024 -> 768 blocks
    gemm256<true><<<dim3((M / 256) * (N1 / 256)), 512, 0, stream>>>(
        xb, wqkvT, b_qkv, qkv, M, N1, C, N1 / 256);
    attn_kernel<<<M / 4, 256, 0, stream>>>(qkv, aout);
    // O-proj: M=16384, N=1024 -> 256 blocks
    gemm256<false><<<dim3((M / 256) * (E / 256)), 512, 0, stream>>>(
        aout, woT, b_o, out, M, E, E, E / 256);
}

// Round 19
// 186.431 us; speedup vs baseline: 1.0057x; 1.0057x over previous
//
#include <hip/hip_runtime.h>
#include <hip/hip_bf16.h>
#include <stdint.h>

#define DEVINLINE __device__ __forceinline__

typedef __attribute__((ext_vector_type(4))) float f32x4;
typedef __attribute__((ext_vector_type(8))) short bf16x8;

DEVINLINE unsigned short f2bf(float f) {
    union { float f; uint32_t u; } v; v.f = f;
    uint32_t u = v.u;
    uint32_t rounding = 0x7FFFu + ((u >> 16) & 1u);
    u += rounding;
    return (unsigned short)(u >> 16);
}

DEVINLINE float bf2f(unsigned short h) {
    union { uint32_t u; float f; } v; v.u = ((uint32_t)h) << 16;
    return v.f;
}

// ---------------- fused prep: x cvt (grid-stride) + w_qkv transpose + w_o transpose ----------------
#define NCVT 1024
__global__ __launch_bounds__(256)
void prep_kernel(const float* __restrict__ x, unsigned short* __restrict__ xb, int n,
                 const float* __restrict__ wq, unsigned short* __restrict__ wqT,
                 const float* __restrict__ wo, unsigned short* __restrict__ woT) {
    int b = blockIdx.x;
    if (b < NCVT) {
        int i = (b * 256 + threadIdx.x) * 4;
        int stride = NCVT * 256 * 4;
        for (; i < n; i += stride) {
            float4 v = *reinterpret_cast<const float4*>(x + i);
            ushort4 o;
            o.x = f2bf(v.x); o.y = f2bf(v.y); o.z = f2bf(v.z); o.w = f2bf(v.w);
            *reinterpret_cast<ushort4*>(xb + i) = o;
        }
        return;
    }
    __shared__ float tile[32][33];
    const float* in;
    unsigned short* outp;
    int R, Ccols, tb;
    if (b < NCVT + 96 * 32) {
        tb = b - NCVT; in = wq; outp = wqT; R = 1024; Ccols = 3072;
    } else {
        tb = b - NCVT - 96 * 32; in = wo; outp = woT; R = 1024; Ccols = 1024;
    }
    int ntx = Ccols / 32;
    int c0 = (tb % ntx) * 32, r0 = (tb / ntx) * 32;
    int tx = threadIdx.x & 31, ty = threadIdx.x >> 5; // 32 x 8
    #pragma unroll
    for (int j = 0; j < 32; j += 8)
        tile[ty + j][tx] = in[(size_t)(r0 + ty + j) * Ccols + c0 + tx];
    __syncthreads();
    #pragma unroll
    for (int j = 0; j < 32; j += 8)
        outp[(size_t)(c0 + ty + j) * R + r0 + tx] = f2bf(tile[tx][ty + j]);
}

// ============ 256x256 bf16 GEMM, read-ahead pipelined (R5/R7 schedule, verified best) ============
// 8 waves (2M x 4N), BK=64, 128 KiB LDS double-buffered.
// Phase p = { MMA(quadrant p); ds_reads for phase p+1; [stages]; [vmcnt]; s_barrier }.
// Quadrants (0,0),(0,1),(1,0),(1,1); reads 4/8/4/8; stages B(tt+2)@p2, A(tt+2)@p3.
// setprio kept (R18 A/B: removal is -1 to -2.5 us on this structure).

#define GLD(srcp, dstp) __builtin_amdgcn_global_load_lds( \
    (const __attribute__((address_space(1))) void*)(srcp), \
    (__attribute__((address_space(3))) void*)(dstp), 16, 0, 0)

// stage one half-tile (128 rows x 64 cols bf16): 2 loads x 8 waves
#define STAGE(P, regionUS, srcBase, row0, kkE) do { \
    const unsigned short* _s = (srcBase) + (size_t)(row0) * K + (kkE); \
    unsigned short* _d = lds + (P) * 32768 + (regionUS) + wid * 512; \
    GLD(_s, _d); GLD(_s + (size_t)64 * K, _d + 4096); } while (0)

#define RD_A(dst, AS0, AS1, h) do { _Pragma("unroll") \
    for (int _i = 0; _i < 4; ++_i) { \
        dst[_i][0] = *(const bf16x8*)((AS0) + ((h) * 8192 + _i * 2048)); \
        dst[_i][1] = *(const bf16x8*)((AS1) + ((h) * 8192 + _i * 2048)); } } while (0)

#define RD_B(dst, BS0, BS1, nh) do { _Pragma("unroll") \
    for (int _j = 0; _j < 2; ++_j) { \
        dst[_j][0] = *(const bf16x8*)((BS0) + ((nh) * 4096 + _j * 2048)); \
        dst[_j][1] = *(const bf16x8*)((BS1) + ((nh) * 4096 + _j * 2048)); } } while (0)

#define MMA(aX, bY, mh, nh) do { \
    __builtin_amdgcn_s_setprio(1); \
    _Pragma("unroll") for (int _i = 0; _i < 4; ++_i) { \
    _Pragma("unroll") for (int _j = 0; _j < 2; ++_j) { \
        acc[(mh)*4+_i][(nh)*2+_j] = __builtin_amdgcn_mfma_f32_16x16x32_bf16( \
            aX[_i][0], bY[_j][0], acc[(mh)*4+_i][(nh)*2+_j], 0, 0, 0); \
        acc[(mh)*4+_i][(nh)*2+_j] = __builtin_amdgcn_mfma_f32_16x16x32_bf16( \
            aX[_i][1], bY[_j][1], acc[(mh)*4+_i][(nh)*2+_j], 0, 0, 0); } } \
    __builtin_amdgcn_s_setprio(0); } while (0)

#define VM4 asm volatile("s_waitcnt vmcnt(4)" ::: "memory")
#define BAR() asm volatile("s_barrier" ::: "memory")

// One K-tile, parity-static LDS addresses. kk = clamped stage source column (elems).
#define KTILE(AS0c, AS1c, BS0c, BS1c, AS0n, AS1n, BS0n, BS1n, Pc, kk) do { \
    MMA(aA, bA, 0, 0); \
    RD_B(bB, BS0c, BS1c, 1); \
    BAR(); \
    MMA(aA, bB, 0, 1); \
    RD_A(aB, AS0c, AS1c, 1); \
    VM4; BAR(); \
    MMA(aB, bA, 1, 0); \
    RD_B(bA, BS0n, BS1n, 0); \
    STAGE(Pc, 16384, bSrc, 0,   kk); \
    STAGE(Pc, 24576, bSrc, 128, kk); \
    VM4; BAR(); \
    MMA(aB, bB, 1, 1); \
    RD_A(aA, AS0n, AS1n, 0); \
    STAGE(Pc, 0,     aSrc, 0,   kk); \
    STAGE(Pc, 8192,  aSrc, 128, kk); \
    BAR(); } while (0)

template <bool OUT_BF16>
__launch_bounds__(512, 2)
__global__ void gemm256(const unsigned short* __restrict__ A,
                        const unsigned short* __restrict__ Bt,
                        const float* __restrict__ bias,
                        void* __restrict__ Cout,
                        int M, int N, int K, int NTN) {
    __shared__ unsigned short lds[65536]; // 128 KiB: 2 buf x (A 256x64 + B 256x64)
    const int NT = K >> 6;                // K-tiles (even, >= 2)

    int t = threadIdx.x;
    int wid = t >> 6, lane = t & 63;
    int wr = wid >> 2, wc = wid & 3;
    int fr = lane & 15, fq = lane >> 4;

    // XCD-aware block swizzle (grid % 8 == 0)
    int nwg = gridDim.x, bid = blockIdx.x;
    int cpx = nwg >> 3;
    int swz = (bid & 7) * cpx + (bid >> 3);
    int tm = swz / NTN, tn = swz % NTN;
    int bm = tm * 256, bn = tn * 256;

    // staging source (per-lane, pre-swizzled 16B slot)
    int rowl = t >> 3, col8 = t & 7;
    int swzcol = (col8 ^ (rowl & 7)) << 3;
    const unsigned short* aSrc = A + (size_t)(bm + rowl) * K + swzcol;
    const unsigned short* bSrc = Bt + (size_t)(bn + rowl) * K + swzcol;

    // ds_read swizzled base pointers (row&7 == fr&7 for all fragment rows)
    int swzm = (fr & 7) << 3;
    int colS0 = (fq << 3) ^ swzm;
    int colS1 = (32 | (fq << 3)) ^ swzm;

    char* ldsb = (char*)lds;
    char* A00 = ldsb + ((wr * 128 + fr) << 7) + 2 * colS0;
    char* A10 = ldsb + ((wr * 128 + fr) << 7) + 2 * colS1;
    char* B00 = ldsb + ((256 + wc * 64 + fr) << 7) + 2 * colS0;
    char* B10 = ldsb + ((256 + wc * 64 + fr) << 7) + 2 * colS1;
    char* A01 = A00 + 65536; char* A11 = A10 + 65536;
    char* B01 = B00 + 65536; char* B11 = B10 + 65536;

    f32x4 acc[8][4] = {};
    bf16x8 aA[4][2], aB[4][2], bA[2][2], bB[2][2];

    // ---- prologue: 16 loads = tiles 0 and 1, order A(0),B(0),B(1),A(1) ----
    STAGE(0, 0,     aSrc, 0,   0);   // A0(0)
    STAGE(0, 8192,  aSrc, 128, 0);   // A1(0)
    STAGE(0, 16384, bSrc, 0,   0);   // B0(0)
    STAGE(0, 24576, bSrc, 128, 0);   // B1(0)
    STAGE(1, 16384, bSrc, 0,   64);  // B0(1)
    STAGE(1, 24576, bSrc, 128, 64);  // B1(1)
    STAGE(1, 0,     aSrc, 0,   64);  // A0(1)
    STAGE(1, 8192,  aSrc, 128, 64);  // A1(1)
    asm volatile("s_waitcnt vmcnt(8)" ::: "memory"); // A(0),B(0) landed
    BAR();
    RD_A(aA, A00, A10, 0);   // A(0) h=0
    RD_B(bA, B00, B10, 0);   // B(0) nh=0

    for (int tau = 0; tau < NT; tau += 2) {
        int kkA = ((tau + 2 < NT) ? (tau + 2) : (NT - 1)) << 6;
        KTILE(A00, A10, B00, B10, A01, A11, B01, B11, 0, kkA);
        int kkB = ((tau + 3 < NT) ? (tau + 3) : (NT - 1)) << 6;
        KTILE(A01, A11, B01, B11, A00, A10, B00, B10, 1, kkB);
    }
    asm volatile("s_waitcnt vmcnt(0)" ::: "memory");

    // ---- epilogue: bias + store ----
    #pragma unroll
    for (int m = 0; m < 8; ++m) {
        #pragma unroll
        for (int n = 0; n < 4; ++n) {
            int col = bn + wc * 64 + n * 16 + fr;
            float bv = bias[col];
            #pragma unroll
            for (int r = 0; r < 4; ++r) {
                int row = bm + wr * 128 + m * 16 + fq * 4 + r;
                float v = acc[m][n][r] + bv;
                if (OUT_BF16)
                    ((unsigned short*)Cout)[(size_t)row * N + col] = f2bf(v);
                else
                    ((float*)Cout)[(size_t)row * N + col] = v;
            }
        }
    }
}

// ---------------- per-position head-mixing attention (MFMA QK^T, 4 pos/block) ----------------
__global__ __launch_bounds__(256)
void attn_kernel(const unsigned short* __restrict__ qkv,
                 unsigned short* __restrict__ out) {
    __shared__ float sv[4][16][68];   // per-wave; row stride 272B (16B-aligned)
    __shared__ float sp[4][16][17];
    int wv = threadIdx.x >> 6;
    int l = threadIdx.x & 63;
    int pos = blockIdx.x * 4 + wv;
    const unsigned short* rowp = qkv + (size_t)pos * 3072;

    #pragma unroll
    for (int j = 0; j < 2; ++j) {
        int i8 = (j * 64 + l) * 8;        // 0..1016
        int h = i8 >> 6, d = i8 & 63;     // h = 0..15
        ushort4 v0 = *reinterpret_cast<const ushort4*>(rowp + h * 192 + 128 + d);
        ushort4 v1 = *reinterpret_cast<const ushort4*>(rowp + h * 192 + 128 + d + 4);
        sv[wv][h][d + 0] = bf2f(v0.x); sv[wv][h][d + 1] = bf2f(v0.y);
        sv[wv][h][d + 2] = bf2f(v0.z); sv[wv][h][d + 3] = bf2f(v0.w);
        sv[wv][h][d + 4] = bf2f(v1.x); sv[wv][h][d + 5] = bf2f(v1.y);
        sv[wv][h][d + 6] = bf2f(v1.z); sv[wv][h][d + 7] = bf2f(v1.w);
    }

    int fr = l & 15, fq = l >> 4;
    const unsigned short* hb = rowp + fr * 192 + fq * 8;
    bf16x8 kf0 = *reinterpret_cast<const bf16x8*>(hb + 64);
    bf16x8 kf1 = *reinterpret_cast<const bf16x8*>(hb + 96);
    bf16x8 qf0 = *reinterpret_cast<const bf16x8*>(hb);
    bf16x8 qf1 = *reinterpret_cast<const bf16x8*>(hb + 32);
    f32x4 st = {};
    st = __builtin_amdgcn_mfma_f32_16x16x32_bf16(kf0, qf0, st, 0, 0, 0);
    st = __builtin_amdgcn_mfma_f32_16x16x32_bf16(kf1, qf1, st, 0, 0, 0);

    float s0 = st[0] * 0.03125f, s1 = st[1] * 0.03125f;
    float s2 = st[2] * 0.03125f, s3 = st[3] * 0.03125f;
    float m = fmaxf(fmaxf(s0, s1), fmaxf(s2, s3));
    m = fmaxf(m, __shfl_xor(m, 16));
    m = fmaxf(m, __shfl_xor(m, 32));
    float e0 = __expf(s0 - m), e1 = __expf(s1 - m);
    float e2 = __expf(s2 - m), e3 = __expf(s3 - m);
    float sum = e0 + e1 + e2 + e3;
    sum += __shfl_xor(sum, 16);
    sum += __shfl_xor(sum, 32);
    float inv = 1.0f / sum;
    sp[wv][fr][fq * 4 + 0] = e0 * inv;
    sp[wv][fr][fq * 4 + 1] = e1 * inv;
    sp[wv][fr][fq * 4 + 2] = e2 * inv;
    sp[wv][fr][fq * 4 + 3] = e3 * inv;
    __syncthreads();

    int h2 = l >> 2, tq = l & 3;
    int dbase = tq * 16;
    float4 o0 = {}, o1 = {}, o2 = {}, o3 = {};
    #pragma unroll
    for (int tt = 0; tt < 16; ++tt) {
        float p = sp[wv][h2][tt];
        float4 v0 = *reinterpret_cast<const float4*>(&sv[wv][tt][dbase + 0]);
        float4 v1 = *reinterpret_cast<const float4*>(&sv[wv][tt][dbase + 4]);
        float4 v2 = *reinterpret_cast<const float4*>(&sv[wv][tt][dbase + 8]);
        float4 v3 = *reinterpret_cast<const float4*>(&sv[wv][tt][dbase + 12]);
        o0.x += p * v0.x; o0.y += p * v0.y; o0.z += p * v0.z; o0.w += p * v0.w;
        o1.x += p * v1.x; o1.y += p * v1.y; o1.z += p * v1.z; o1.w += p * v1.w;
        o2.x += p * v2.x; o2.y += p * v2.y; o2.z += p * v2.z; o2.w += p * v2.w;
        o3.x += p * v3.x; o3.y += p * v3.y; o3.z += p * v3.z; o3.w += p * v3.w;
    }
    ushort4* po = (ushort4*)(out + (size_t)pos * 1024 + h2 * 64 + dbase);
    ushort4 w0 = { f2bf(o0.x), f2bf(o0.y), f2bf(o0.z), f2bf(o0.w) };
    ushort4 w1 = { f2bf(o1.x), f2bf(o1.y), f2bf(o1.z), f2bf(o1.w) };
    ushort4 w2 = { f2bf(o2.x), f2bf(o2.y), f2bf(o2.z), f2bf(o2.w) };
    ushort4 w3 = { f2bf(o3.x), f2bf(o3.y), f2bf(o3.z), f2bf(o3.w) };
    po[0] = w0; po[1] = w1; po[2] = w2; po[3] = w3;
}

extern "C" void kernel_launch(void* const* d_in, const int* in_sizes, int n_in,
                              void* d_out, int out_size, void* d_ws, size_t ws_size,
                              hipStream_t stream) {
    const float* x     = (const float*)d_in[0];
    const float* w_qkv = (const float*)d_in[1];
    const float* b_qkv = (const float*)d_in[2];
    const float* w_o   = (const float*)d_in[3];
    const float* b_o   = (const float*)d_in[4];
    float* out = (float*)d_out;

    const int C = 1024, E = 1024;
    const int M = 16 * 1024;      // B*S = 16384
    const int N1 = 3 * E;         // 3072

    char* ws = (char*)d_ws;
    unsigned short* xb    = (unsigned short*)ws;            // M*C bf16
    unsigned short* wqkvT = xb    + (size_t)M * C;          // N1*C
    unsigned short* qkv   = wqkvT + (size_t)N1 * C;         // M*N1
    unsigned short* woT   = qkv   + (size_t)M * N1;         // E*E
    unsigned short* aout  = woT   + (size_t)E * E;          // M*E

    prep_kernel<<<NCVT + 96 * 32 + 32 * 32, 256, 0, stream>>>(
        x, xb, M * C, w_qkv, wqkvT, w_o, woT);

    // QKV: M=16384, N=3072, K=1024 -> 768 blocks
    gemm256<true><<<dim3((M / 256) * (N1 / 256)), 512, 0, stream>>>(
        xb, wqkvT, b_qkv, qkv, M, N1, C, N1 / 256);
    attn_kernel<<<M / 4, 256, 0, stream>>>(qkv, aout);
    // O-proj: M=16384, N=1024 -> 256 blocks
    gemm256<false><<<dim3((M / 256) * (E / 256)), 512, 0, stream>>>(
        aout, woT, b_o, out, M, E, E, E / 256);
}